// Round 2
// baseline (107506.116 us; speedup 1.0000x reference)
//
#include <hip/hip_runtime.h>
#include <hip/hip_bf16.h>
#include <math.h>

// Problem constants: V=32000, D=256, H=256, L=2, C=2, B=64, T=1024, PAD=0
namespace {
constexpr int Bn = 64;
constexpr int Tn = 1024;
constexpr int Dn = 256;
constexpr int Hn = 256;
}

template <typename T>
__device__ __forceinline__ float ldf(const T* p, long i);
template <>
__device__ __forceinline__ float ldf<float>(const float* p, long i) { return p[i]; }
template <>
__device__ __forceinline__ float ldf<__hip_bfloat16>(const __hip_bfloat16* p, long i) {
  return __bfloat162float(p[i]);
}

// ---------------------------------------------------------------------------
// Dtype detector: read first 4096 u16 words of E. If data is f32, ~46% of the
// garbage (low-mantissa) halves have bf16-exponent >= 137 (|x|>1024 or NaN).
// Real bf16 N(0,0.02) data has none. flag=1 -> float32 inputs.
// ---------------------------------------------------------------------------
__global__ void k_detect(const unsigned short* __restrict__ e, int* __restrict__ flag) {
  __shared__ int sbuf[256];
  int bad = 0;
  for (int i = threadIdx.x; i < 4096; i += 256) {
    const unsigned short v = e[i];
    const int ex = (v >> 7) & 0xFF;
    bad += (ex >= 137) ? 1 : 0;
  }
  sbuf[threadIdx.x] = bad;
  __syncthreads();
  for (int s = 128; s > 0; s >>= 1) {
    if (threadIdx.x < s) sbuf[threadIdx.x] += sbuf[threadIdx.x + s];
    __syncthreads();
  }
  if (threadIdx.x == 0) flag[0] = (sbuf[0] > 64) ? 1 : 0;
}

// ---------------------------------------------------------------------------
__global__ void k_lengths(const int* __restrict__ x, int* __restrict__ len) {
  const int b = blockIdx.x;
  int cnt = 0;
  for (int t = threadIdx.x; t < Tn; t += blockDim.x) cnt += (x[b * Tn + t] != 0) ? 1 : 0;
  __shared__ int sbuf[256];
  sbuf[threadIdx.x] = cnt;
  __syncthreads();
  for (int s = 128; s > 0; s >>= 1) {
    if (threadIdx.x < s) sbuf[threadIdx.x] += sbuf[threadIdx.x + s];
    __syncthreads();
  }
  if (threadIdx.x == 0) len[b] = sbuf[0];
}

// ---------------------------------------------------------------------------
// One workgroup = one (batch b, direction dir). Thread j owns hidden unit j.
// TW: dtype of E / W / bias. Intermediate sequence scratch is ALWAYS bf16.
// ---------------------------------------------------------------------------
template <typename TW, int XK, bool WRITE_SEQ>
__device__ __forceinline__ void lstm_body(const int* __restrict__ x, const TW* __restrict__ E,
                                          const __hip_bfloat16* __restrict__ seq_in,
                                          const TW* __restrict__ W, const TW* __restrict__ bias,
                                          const int len, const int b, const int dir,
                                          __hip_bfloat16* __restrict__ seq_out,
                                          float* __restrict__ hfin) {
  const int j = threadIdx.x;  // 0..255

  __shared__ float h[Hn];
  __shared__ float xb[XK];

  float hj = 0.0f;
  float cj = 0.0f;
  h[j] = 0.0f;

  const float bfj = ldf(bias, j);
  const float bij = ldf(bias, Hn + j);
  const float bgj = ldf(bias, 2 * Hn + j);
  const float boj = ldf(bias, 3 * Hn + j);
  __syncthreads();

  for (int s = 0; s < Tn; ++s) {
    const int t = dir ? (Tn - 1 - s) : s;
    const bool active = (t < len);  // uniform across the block
    if (active) {
      if constexpr (XK == Dn) {
        const int tok = x[b * Tn + t];
        xb[j] = ldf(E, (long)tok * Dn + j);
      } else {
        const long base = ((long)(b * Tn + t)) * (2 * Hn);
        xb[j] = __bfloat162float(seq_in[base + j]);
        xb[j + Hn] = __bfloat162float(seq_in[base + j + Hn]);
      }
      __syncthreads();

      float af = bfj, ai = bij, ag = bgj, ao = boj;
#pragma unroll 4
      for (int k = 0; k < Hn; ++k) {
        const float hk = h[k];
        const long r = (long)k * (4 * Hn);
        af += hk * ldf(W, r + j);
        ai += hk * ldf(W, r + Hn + j);
        ag += hk * ldf(W, r + 2 * Hn + j);
        ao += hk * ldf(W, r + 3 * Hn + j);
      }
#pragma unroll 4
      for (int k = 0; k < XK; ++k) {
        const float xk = xb[k];
        const long r = (long)(Hn + k) * (4 * Hn);
        af += xk * ldf(W, r + j);
        ai += xk * ldf(W, r + Hn + j);
        ag += xk * ldf(W, r + 2 * Hn + j);
        ao += xk * ldf(W, r + 3 * Hn + j);
      }

      const float fg = 1.0f / (1.0f + expf(-af));
      const float ig = 1.0f / (1.0f + expf(-ai));
      const float gg = tanhf(ag);
      const float og = 1.0f / (1.0f + expf(-ao));
      const float cn = fg * cj + ig * gg;
      const float hn = og * tanhf(cn);

      __syncthreads();  // all reads of h[]/xb[] for this step done
      hj = hn;
      cj = cn;
      h[j] = hn;
      __syncthreads();  // h[] updated before next step
    }
    if constexpr (WRITE_SEQ) {
      seq_out[((long)(b * Tn + t)) * (2 * Hn) + dir * Hn + j] = __float2bfloat16(hj);
    }
  }
  if constexpr (!WRITE_SEQ) {
    hfin[(dir * Bn + b) * Hn + j] = hj;
  }
}

template <int XK, bool WRITE_SEQ>
__global__ void k_lstm(const int* __restrict__ x, const void* __restrict__ E,
                       const __hip_bfloat16* __restrict__ seq_in, const void* __restrict__ Wf,
                       const void* __restrict__ bf, const void* __restrict__ Wb,
                       const void* __restrict__ bb, const int* __restrict__ lengths,
                       const int* __restrict__ flag, __hip_bfloat16* __restrict__ seq_out,
                       float* __restrict__ hfin) {
  const int b = blockIdx.x & (Bn - 1);
  const int dir = blockIdx.x >> 6;
  const int len = lengths[b];
  const void* W = dir ? Wb : Wf;
  const void* bias = dir ? bb : bf;
  if (flag[0]) {
    lstm_body<float, XK, WRITE_SEQ>(x, (const float*)E, seq_in, (const float*)W,
                                    (const float*)bias, len, b, dir, seq_out, hfin);
  } else {
    lstm_body<__hip_bfloat16, XK, WRITE_SEQ>(x, (const __hip_bfloat16*)E, seq_in,
                                             (const __hip_bfloat16*)W, (const __hip_bfloat16*)bias,
                                             len, b, dir, seq_out, hfin);
  }
}

// ---------------------------------------------------------------------------
template <typename TW>
__device__ __forceinline__ void fc_body(const float* __restrict__ hfin, const TW* __restrict__ Wfc,
                                        const TW* __restrict__ bfc, TW* __restrict__ out) {
  const int idx = threadIdx.x;  // 0..127
  const int b = idx >> 1;
  const int cc = idx & 1;
  float acc = ldf(bfc, cc);
  for (int k = 0; k < Hn; ++k) acc += hfin[(0 * Bn + b) * Hn + k] * ldf(Wfc, k * 2 + cc);
  for (int k = 0; k < Hn; ++k) acc += hfin[(1 * Bn + b) * Hn + k] * ldf(Wfc, (Hn + k) * 2 + cc);
  if constexpr (sizeof(TW) == 2) {
    out[b * 2 + cc] = __float2bfloat16(acc);
  } else {
    out[b * 2 + cc] = acc;
  }
}

__global__ void k_fc(const float* __restrict__ hfin, const void* __restrict__ Wfc,
                     const void* __restrict__ bfc, const int* __restrict__ flag,
                     void* __restrict__ out) {
  if (flag[0]) {
    fc_body<float>(hfin, (const float*)Wfc, (const float*)bfc, (float*)out);
  } else {
    fc_body<__hip_bfloat16>(hfin, (const __hip_bfloat16*)Wfc, (const __hip_bfloat16*)bfc,
                            (__hip_bfloat16*)out);
  }
}

// ---------------------------------------------------------------------------
extern "C" void kernel_launch(void* const* d_in, const int* in_sizes, int n_in,
                              void* d_out, int out_size, void* d_ws, size_t ws_size,
                              hipStream_t stream) {
  const int* x = (const int*)d_in[0];
  const void* E = d_in[1];
  const void* Wf0 = d_in[2];
  const void* bf0 = d_in[3];
  const void* Wb0 = d_in[4];
  const void* bb0 = d_in[5];
  const void* Wf1 = d_in[6];
  const void* bf1 = d_in[7];
  const void* Wb1 = d_in[8];
  const void* bb1 = d_in[9];
  const void* Wfc = d_in[10];
  const void* bfc = d_in[11];

  char* ws = (char*)d_ws;
  int* flag = (int*)ws;                                  // 4 B
  int* lengths = (int*)(ws + 256);                       // 256 B
  __hip_bfloat16* seq0 = (__hip_bfloat16*)(ws + 4096);   // B*T*2H bf16 = 64 MiB
  const size_t seq0_bytes = (size_t)Bn * Tn * 2 * Hn * sizeof(__hip_bfloat16);
  float* hfin = (float*)(ws + 4096 + seq0_bytes);        // 2*B*H f32 = 128 KiB

  k_detect<<<1, 256, 0, stream>>>((const unsigned short*)E, flag);
  k_lengths<<<Bn, 256, 0, stream>>>(x, lengths);
  k_lstm<Dn, true><<<2 * Bn, 256, 0, stream>>>(x, E, nullptr, Wf0, bf0, Wb0, bb0, lengths, flag,
                                               seq0, nullptr);
  k_lstm<2 * Hn, false><<<2 * Bn, 256, 0, stream>>>(x, E, seq0, Wf1, bf1, Wb1, bb1, lengths, flag,
                                                    nullptr, hfin);
  k_fc<<<1, 128, 0, stream>>>(hfin, Wfc, bfc, flag, d_out);
}